// Round 3
// baseline (264.874 us; speedup 1.0000x reference)
//
#include <hip/hip_runtime.h>
#include <hip/hip_bf16.h>

typedef float f32x4 __attribute__((ext_vector_type(4)));
typedef short bf16x8 __attribute__((ext_vector_type(8)));

#define MFMA16(a, b, c) __builtin_amdgcn_mfma_f32_16x16x32_bf16(a, b, c, 0, 0, 0)

// Problem constants
constexpr int K1  = 940;    // IN_F
constexpr int KP2 = 1024;   // w2 K stride (zero-padded)
constexpr int NP  = 112;    // N=100 padded to 7 tiles of 16
constexpr int OSL = 136;    // out_s LDS row stride (bf16): 272B -> 2-way banks

__device__ __forceinline__ float sigf(float x) { return 1.f / (1.f + __expf(-x)); }
__device__ __forceinline__ float tanhfast(float x) { return 2.f / (1.f + __expf(-2.f * x)) - 1.f; }

__device__ __forceinline__ short f2b(float x) {
  __hip_bfloat16 b = __float2bfloat16(x);
  return *reinterpret_cast<short*>(&b);
}

// ---------------------------------------------------------------------------
// Prep: fold swapaxes(-1,-2) into the weights, convert fp32->bf16, zero-pad.
// w2[n][k] zero for k>=940 or n>=100; bw2 K-padded 100->128.
// ---------------------------------------------------------------------------
__global__ void prep_kernel(const float* __restrict__ lin_w,
                            const float* __restrict__ b_wih,
                            __hip_bfloat16* __restrict__ w2,
                            __hip_bfloat16* __restrict__ bw2) {
  int idx = blockIdx.x * 256 + threadIdx.x;
  if (idx < NP * KP2) {
    int n = idx >> 10, k = idx & 1023;
    float v = 0.f;
    if (n < 100 && k < K1) {
      int c10 = k / 94, rem = k - c10 * 94;
      int c2 = rem / 47, c47 = rem - c2 * 47;
      int f = c10 * 94 + c47 * 2 + c2;
      v = lin_w[n * K1 + f];
    }
    w2[idx] = __float2bfloat16(v);
  } else {
    int i2 = idx - NP * KP2;
    if (i2 < 64 * 128) {
      int g = i2 >> 7, k = i2 & 127;
      bw2[i2] = __float2bfloat16((k < 100) ? b_wih[g * 100 + k] : 0.f);
    }
  }
}

// ---------------------------------------------------------------------------
// Mega-fused, BARRIER-FREE version. Block = 256 threads = 4 waves, 64 rows.
// Wave w owns rows w*16..w*16+15 END-TO-END:
//   Phase A: full-K GEMM for its 16 rows x 112 cols. A (channels fp32) from
//            HBM, double-buffered 64-k chunks; B (w2) streamed per k-step
//            from global (215 KB, L2/L1-hot across all waves). No split-K,
//            no red buffer, NO barriers.
//   Phase B: xg for its 16 rows (out_s rows are wave-private -> same-wave
//            LDS RAW, ordered by lgkmcnt, no barrier).
//   Phase C: its 2 frac-sequences (rows 16w..16w+7, 16w+8..16w+15),
//            interleaved for ILP.
// K trimmed to 30 k-steps (960): k>=940 contributes 0 (w2 zero-padded);
// k-step 29 masks A loads at float4 granularity to avoid OOB on last row.
// launch_bounds (256,2): VGPR cap 256 -- ~150 needed, zero spill risk, and
// 2 waves/SIMD suffices for the grid's 8 waves/CU (512 blocks / 256 CUs).
// ---------------------------------------------------------------------------
__global__ __launch_bounds__(256, 2)
void fused_encoder(const float* __restrict__ ch,
                   const __hip_bfloat16* __restrict__ w2,
                   const float* __restrict__ lin_b,
                   const __hip_bfloat16* __restrict__ bw2,
                   const float* __restrict__ bih,
                   const float* __restrict__ bhh,
                   const float* __restrict__ whh,
                   float* __restrict__ beats) {
  __shared__ __align__(16) __hip_bfloat16 out_s[64 * OSL];  // 17408 B
  __shared__ float xg_s[64 * 65];                           // 16640 B

  const int tid = threadIdx.x;
  const int w = tid >> 6, lane = tid & 63;
  const int l16 = lane & 15, bq = lane >> 4;

  const int mbase = blockIdx.x * 64 + w * 16;        // wave's first row
  const float* ar = ch + (long)(mbase + l16) * K1 + bq * 8;

  // per-lane element index into w2 for each n-tile (k-step adds ks*32)
  int bidx[7];
#pragma unroll
  for (int nt = 0; nt < 7; ++nt) bidx[nt] = (nt * 16 + l16) * KP2 + bq * 8;

  float lb[7];
#pragma unroll
  for (int nt = 0; nt < 7; ++nt) {
    int col = nt * 16 + l16;
    lb[nt] = (col < 100) ? lin_b[col] : 0.f;
  }

  auto mk = [&](float4 lo, float4 hi) -> bf16x8 {
    return bf16x8{f2b(lo.x), f2b(lo.y), f2b(lo.z), f2b(lo.w),
                  f2b(hi.x), f2b(hi.y), f2b(hi.z), f2b(hi.w)};
  };

  // ---- Phase A: per-wave full-K GEMM, no barriers ----
  f32x4 acc[7] = {};
  float4 Ab[2][4];   // chunk = 2 k-steps = 16 fp32/lane; double-buffered
  bf16x8 Bb[2][7];   // per-k-step B fragments, ping-pong

  const float4 f40{0.f, 0.f, 0.f, 0.f};
  // chunk c covers k-steps 2c, 2c+1 (k = c*64 .. c*64+63)
  auto ldA = [&](int c, float4* d) {
    const float* p = ar + c * 64;
    if (c < 14) {
      d[0] = *reinterpret_cast<const float4*>(p);
      d[1] = *reinterpret_cast<const float4*>(p + 4);
      d[2] = *reinterpret_cast<const float4*>(p + 32);
      d[3] = *reinterpret_cast<const float4*>(p + 36);
    } else {  // c == 14: k-step 28 full (k<=927), k-step 29 masked (k<940)
      d[0] = *reinterpret_cast<const float4*>(p);
      d[1] = *reinterpret_cast<const float4*>(p + 4);
      d[2] = (bq <= 1) ? *reinterpret_cast<const float4*>(p + 32) : f40;  // k 928+bq*8..+3
      d[3] = (bq == 0) ? *reinterpret_cast<const float4*>(p + 36) : f40;  // k 932..935
    }
  };
  auto ldB = [&](int ks, bf16x8* d) {
#pragma unroll
    for (int nt = 0; nt < 7; ++nt)
      d[nt] = *reinterpret_cast<const bf16x8*>(&w2[bidx[nt] + ks * 32]);
  };

  ldA(0, Ab[0]);
  ldB(0, Bb[0]);
  ldB(1, Bb[1]);
#pragma unroll
  for (int c = 0; c < 15; ++c) {
    float4* A = Ab[c & 1];
    if (c < 14) ldA(c + 1, Ab[(c + 1) & 1]);  // HBM prefetch, 1 chunk ahead
    {
      bf16x8 a = mk(A[0], A[1]);
#pragma unroll
      for (int nt = 0; nt < 7; ++nt) acc[nt] = MFMA16(a, Bb[0][nt], acc[nt]);
    }
    if (c < 14) ldB(2 * c + 2, Bb[0]);        // refill after last use
    {
      bf16x8 a = mk(A[2], A[3]);
#pragma unroll
      for (int nt = 0; nt < 7; ++nt) acc[nt] = MFMA16(a, Bb[1][nt], acc[nt]);
    }
    if (c < 14) ldB(2 * c + 3, Bb[1]);
  }

  // epilogue: bias + relu -> out_s (wave-private rows), zero-pad cols 100..127
#pragma unroll
  for (int nt = 0; nt < 7; ++nt) {
    const int col = nt * 16 + l16;
#pragma unroll
    for (int r = 0; r < 4; ++r) {
      float v = fmaxf(acc[nt][r] + lb[nt], 0.f);
      out_s[(w * 16 + bq * 4 + r) * OSL + col] = __float2bfloat16((col < 100) ? v : 0.f);
    }
  }
#pragma unroll
  for (int r = 0; r < 4; ++r)
    out_s[(w * 16 + bq * 4 + r) * OSL + 112 + l16] = __float2bfloat16(0.f);

  // ---- Phase B: xg[16 rows][64 gates] for this wave's rows. No barrier:
  // reads exactly the out_s rows this wave wrote (lgkmcnt orders it). ----
  {
    bf16x8 av[4];
#pragma unroll
    for (int s = 0; s < 4; ++s)
      av[s] = *reinterpret_cast<const bf16x8*>(&out_s[(w * 16 + l16) * OSL + s * 32 + bq * 8]);
    f32x4 xacc[4] = {};
#pragma unroll
    for (int gt = 0; gt < 4; ++gt) {
#pragma unroll
      for (int s = 0; s < 4; ++s) {
        bf16x8 b = *reinterpret_cast<const bf16x8*>(&bw2[(gt * 16 + l16) * 128 + s * 32 + bq * 8]);
        xacc[gt] = MFMA16(av[s], b, xacc[gt]);
      }
    }
#pragma unroll
    for (int gt = 0; gt < 4; ++gt) {
      const int gate = gt * 16 + l16;
      const float bias = bih[gate] + bhh[gate];
#pragma unroll
      for (int r = 0; r < 4; ++r)
        xg_s[(w * 16 + bq * 4 + r) * 65 + gate] = xacc[gt][r] + bias;
    }
  }

  // ---- Phase C: beats LSTM, 2 sequences per wave, interleaved. No barrier:
  // xg_s rows 16w..16w+15 are exactly this wave's Phase-B output. ----
  {
    const int cell = lane & 15;
    float wr[16];
#pragma unroll
    for (int u = 0; u < 16; ++u) wr[u] = whh[lane * 16 + u];
    float xv0[8], xv1[8];
#pragma unroll
    for (int t = 0; t < 8; ++t) {
      xv0[t] = xg_s[(w * 16 + t) * 65 + lane];
      xv1[t] = xg_s[(w * 16 + 8 + t) * 65 + lane];
    }
    float h0[16], h1[16];
#pragma unroll
    for (int u = 0; u < 16; ++u) { h0[u] = 0.f; h1[u] = 0.f; }
    float c0 = 0.f, c1 = 0.f;
    const long sg0 = (long)blockIdx.x * 8 + 2 * w;
    const long sg1 = sg0 + 1;
#pragma unroll
    for (int t = 0; t < 8; ++t) {
      float p0 = xv0[t], p1 = xv1[t];
#pragma unroll
      for (int u = 0; u < 16; ++u) { p0 += wr[u] * h0[u]; p1 += wr[u] * h1[u]; }
      const bool istanh = (lane >= 32 && lane < 48);
      float a0 = istanh ? tanhfast(p0) : sigf(p0);
      float a1 = istanh ? tanhfast(p1) : sigf(p1);
      float gi0 = __shfl(a0, cell),      gi1 = __shfl(a1, cell);
      float gf0 = __shfl(a0, cell + 16), gf1 = __shfl(a1, cell + 16);
      float gg0 = __shfl(a0, cell + 32), gg1 = __shfl(a1, cell + 32);
      float go0 = __shfl(a0, cell + 48), go1 = __shfl(a1, cell + 48);
      c0 = gf0 * c0 + gi0 * gg0;
      c1 = gf1 * c1 + gi1 * gg1;
      float hn0 = go0 * tanhfast(c0);
      float hn1 = go1 * tanhfast(c1);
#pragma unroll
      for (int u = 0; u < 16; ++u) { h0[u] = __shfl(hn0, u); h1[u] = __shfl(hn1, u); }
      if (lane < 16) {
        beats[sg0 * 128 + t * 16 + lane] = hn0;
        beats[sg1 * 128 + t * 16 + lane] = hn1;
      }
    }
  }
}

// ---------------------------------------------------------------------------
// Phase 3: bars biLSTM. 1024 seqs, T=4(beats), H=32. Block = 1 seq,
// 256 threads = 2 dirs x 128 gates.
// ---------------------------------------------------------------------------
__global__ __launch_bounds__(256)
void bars_bilstm(const float* __restrict__ fwih, const float* __restrict__ fwhh,
                 const float* __restrict__ fbih, const float* __restrict__ fbhh,
                 const float* __restrict__ rwih, const float* __restrict__ rwhh,
                 const float* __restrict__ rbih, const float* __restrict__ rbhh,
                 const float* __restrict__ beats,
                 float* __restrict__ bars) {
  const int tid = threadIdx.x;
  const int dir = tid >> 7, g = tid & 127;
  const int n = blockIdx.x;
  const float* wih = dir ? rwih : fwih;
  const float* whh = dir ? rwhh : fwhh;
  const float bias = dir ? (rbih[g] + rbhh[g]) : (fbih[g] + fbhh[g]);
  float wi[16], wh[32];
#pragma unroll
  for (int u = 0; u < 16; ++u) wi[u] = wih[g * 16 + u];
#pragma unroll
  for (int u = 0; u < 32; ++u) wh[u] = whh[g * 32 + u];
  __shared__ float xbuf[2][16];
  __shared__ float hbuf[2][32];
  __shared__ float gact[2][128];
  float c = 0.f;
  if (g < 32) hbuf[dir][g] = 0.f;
  __syncthreads();
  for (int t = 0; t < 4; ++t) {
    const int tt = dir ? (3 - t) : t;
    if (g < 16) xbuf[dir][g] = beats[((n * 4 + tt) * 8 + 7) * 16 + g];
    __syncthreads();
    float pre = bias;
#pragma unroll
    for (int u = 0; u < 16; ++u) pre += wi[u] * xbuf[dir][u];
#pragma unroll
    for (int u = 0; u < 32; ++u) pre += wh[u] * hbuf[dir][u];
    gact[dir][g] = (g >= 64 && g < 96) ? tanhfast(pre) : sigf(pre);
    __syncthreads();
    if (g < 32) {
      c = gact[dir][32 + g] * c + gact[dir][g] * gact[dir][64 + g];
      float hn = gact[dir][96 + g] * tanhfast(c);
      hbuf[dir][g] = hn;
      bars[(n * 4 + tt) * 64 + dir * 32 + g] = hn;
    }
    __syncthreads();
  }
}

extern "C" void kernel_launch(void* const* d_in, const int* in_sizes, int n_in,
                              void* d_out, int out_size, void* d_ws, size_t ws_size,
                              hipStream_t stream) {
  const float* ch    = (const float*)d_in[0];
  const float* lin_w = (const float*)d_in[1];
  const float* lin_b = (const float*)d_in[2];
  const float* b_wih = (const float*)d_in[3];
  const float* b_whh = (const float*)d_in[4];
  const float* b_bih = (const float*)d_in[5];
  const float* b_bhh = (const float*)d_in[6];
  const float* f_wih = (const float*)d_in[7];
  const float* f_whh = (const float*)d_in[8];
  const float* f_bih = (const float*)d_in[9];
  const float* f_bhh = (const float*)d_in[10];
  const float* r_wih = (const float*)d_in[11];
  const float* r_whh = (const float*)d_in[12];
  const float* r_bih = (const float*)d_in[13];
  const float* r_bhh = (const float*)d_in[14];

  char* ws = (char*)d_ws;
  __hip_bfloat16* w2  = (__hip_bfloat16*)ws;             // 112*1024*2 = 229376 B
  __hip_bfloat16* bw2 = (__hip_bfloat16*)(ws + 229376);  // 64*128*2   = 16384 B
  float*          out = (float*)d_out;

  prep_kernel<<<480, 256, 0, stream>>>(lin_w, b_wih, w2, bw2);
  fused_encoder<<<512, 256, 0, stream>>>(ch, w2, lin_b, bw2, b_bih, b_bhh,
                                         b_whh, out);
  bars_bilstm<<<1024, 256, 0, stream>>>(f_wih, f_whh, f_bih, f_bhh,
                                        r_wih, r_whh, r_bih, r_bhh,
                                        out, out + 524288);
}

// Round 4
// 230.399 us; speedup vs baseline: 1.1496x; 1.1496x over previous
//
#include <hip/hip_runtime.h>
#include <hip/hip_bf16.h>

typedef float f32x4 __attribute__((ext_vector_type(4)));
typedef short bf16x8 __attribute__((ext_vector_type(8)));

#define MFMA16(a, b, c) __builtin_amdgcn_mfma_f32_16x16x32_bf16(a, b, c, 0, 0, 0)

// Problem constants
constexpr int K1  = 940;    // IN_F
constexpr int KP2 = 1024;   // w2 K stride (zero-padded)
constexpr int NP  = 112;    // N=100 padded to 7 tiles of 16
constexpr int OSL = 136;    // out_s LDS row stride (bf16): 272B -> 2-way banks
constexpr int BSR = 72;     // Bs LDS row stride (bf16): 144B, 16B-aligned, bank offset 4 dw

__device__ __forceinline__ float sigf(float x) { return 1.f / (1.f + __expf(-x)); }
__device__ __forceinline__ float tanhfast(float x) { return 2.f / (1.f + __expf(-2.f * x)) - 1.f; }

__device__ __forceinline__ short f2b(float x) {
  __hip_bfloat16 b = __float2bfloat16(x);
  return *reinterpret_cast<short*>(&b);
}

// ---------------------------------------------------------------------------
// Prep: fold swapaxes(-1,-2) into the weights, convert fp32->bf16, zero-pad.
// w2[n][k] zero for k>=940 or n>=100; bw2 K-padded 100->128.
// ---------------------------------------------------------------------------
__global__ void prep_kernel(const float* __restrict__ lin_w,
                            const float* __restrict__ b_wih,
                            __hip_bfloat16* __restrict__ w2,
                            __hip_bfloat16* __restrict__ bw2) {
  int idx = blockIdx.x * 256 + threadIdx.x;
  if (idx < NP * KP2) {
    int n = idx >> 10, k = idx & 1023;
    float v = 0.f;
    if (n < 100 && k < K1) {
      int c10 = k / 94, rem = k - c10 * 94;
      int c2 = rem / 47, c47 = rem - c2 * 47;
      int f = c10 * 94 + c47 * 2 + c2;
      v = lin_w[n * K1 + f];
    }
    w2[idx] = __float2bfloat16(v);
  } else {
    int i2 = idx - NP * KP2;
    if (i2 < 64 * 128) {
      int g = i2 >> 7, k = i2 & 127;
      bw2[i2] = __float2bfloat16((k < 100) ? b_wih[g * 100 + k] : 0.f);
    }
  }
}

// ---------------------------------------------------------------------------
// Canonical staged GEMM + fused LSTM. Block = 256 threads = 4 waves, 64 rows.
// Wave w owns rows w*16..w*16+15 END-TO-END (no split-K, acc in AGPRs).
//   B (w2): staged chunk-wise (112 x 64k, 14 KB) into double-buffered LDS.
//           Stage loads for chunk c+1 issued BEFORE computing chunk c
//           (global latency hidden under a full chunk of compute);
//           ds_writes land after compute; ONE barrier per chunk.
//   A (channels): HBM, double-buffered one chunk ahead, off critical path.
//   Phase B/C: wave-private rows in out_s/xg_s, barrier-free (R3's design).
// LDS union: Bs[2] (32256 B, Phase A) and out_s+xg_s (34048 B, Phase B/C)
// are separated by the final chunk barrier -> total 34048 B.
// launch_bounds (256,2): cap 256 VGPR >= ~130 needed; cap>need is harmless
// (R1: cap<need forced spills -- never cap below requirement).
// ---------------------------------------------------------------------------
__global__ __launch_bounds__(256, 2)
void fused_encoder(const float* __restrict__ ch,
                   const __hip_bfloat16* __restrict__ w2,
                   const float* __restrict__ lin_b,
                   const __hip_bfloat16* __restrict__ bw2,
                   const float* __restrict__ bih,
                   const float* __restrict__ bhh,
                   const float* __restrict__ whh,
                   float* __restrict__ beats) {
  __shared__ __align__(16) char smem[34048];
  __hip_bfloat16* Bs    = reinterpret_cast<__hip_bfloat16*>(smem);  // 2*112*BSR*2 = 32256
  __hip_bfloat16* out_s = reinterpret_cast<__hip_bfloat16*>(smem);  // 64*OSL*2 = 17408
  float*          xg_s  = reinterpret_cast<float*>(smem + 17408);   // 64*65*4  = 16640

  const int tid = threadIdx.x;
  const int w = tid >> 6, lane = tid & 63;
  const int l16 = lane & 15, bq = lane >> 4;

  const int mbase = blockIdx.x * 64 + w * 16;        // wave's first row
  const float* ar = ch + (long)(mbase + l16) * K1 + bq * 8;

  float lb[7];
#pragma unroll
  for (int nt = 0; nt < 7; ++nt) {
    int col = nt * 16 + l16;
    lb[nt] = (col < 100) ? lin_b[col] : 0.f;
  }

  auto mk = [&](float4 lo, float4 hi) -> bf16x8 {
    return bf16x8{f2b(lo.x), f2b(lo.y), f2b(lo.z), f2b(lo.w),
                  f2b(hi.x), f2b(hi.y), f2b(hi.z), f2b(hi.w)};
  };

  // ---- Phase A ----
  f32x4 acc[7] = {};
  float4 Ab[2][4];   // A chunk = 64 k = 16 fp32/lane, double-buffered
  bf16x8 bst[4];     // B staging registers (global -> LDS)

  const float4 f40{0.f, 0.f, 0.f, 0.f};
  // A chunk c covers k = c*64 .. c*64+63
  auto ldA = [&](int c, float4* d) {
    const float* p = ar + c * 64;
    if (c < 14) {
      d[0] = *reinterpret_cast<const float4*>(p);
      d[1] = *reinterpret_cast<const float4*>(p + 4);
      d[2] = *reinterpret_cast<const float4*>(p + 32);
      d[3] = *reinterpret_cast<const float4*>(p + 36);
    } else {  // c == 14: k 896..927 full, k 928..939 partial (k<940 valid)
      d[0] = *reinterpret_cast<const float4*>(p);
      d[1] = *reinterpret_cast<const float4*>(p + 4);
      d[2] = (bq <= 1) ? *reinterpret_cast<const float4*>(p + 32) : f40;
      d[3] = (bq == 0) ? *reinterpret_cast<const float4*>(p + 36) : f40;
    }
  };

  // B staging: thread t -> row sn = t>>1, k-half skh = (t&1)*32 (32 bf16 = 4x16B)
  const int sn = tid >> 1, skh = (tid & 1) * 32;
  auto stageB_ld = [&](int c) {
    if (sn < NP) {
      const __hip_bfloat16* src = w2 + sn * KP2 + c * 64 + skh;
#pragma unroll
      for (int j = 0; j < 4; ++j)
        bst[j] = *reinterpret_cast<const bf16x8*>(src + j * 8);
    }
  };
  auto stageB_st = [&](int buf) {
    if (sn < NP) {
      __hip_bfloat16* dst = Bs + buf * (NP * BSR) + sn * BSR + skh;
#pragma unroll
      for (int j = 0; j < 4; ++j)
        *reinterpret_cast<bf16x8*>(dst + j * 8) = bst[j];
    }
  };

  // prologue: chunk 0 staged, A chunk 0 in regs
  stageB_ld(0);
  stageB_st(0);
  ldA(0, Ab[0]);
  __syncthreads();

  for (int c = 0; c < 15; ++c) {
    if (c < 14) {
      stageB_ld(c + 1);              // global B loads: land during compute
      ldA(c + 1, Ab[(c + 1) & 1]);   // HBM A prefetch, one chunk ahead
    }
    // compute chunk c from Bs[c&1]
    const __hip_bfloat16* Bc = Bs + (c & 1) * (NP * BSR);
    float4* A = Ab[c & 1];
#pragma unroll
    for (int ks = 0; ks < 2; ++ks) {
      bf16x8 bf[7];
#pragma unroll
      for (int nt = 0; nt < 7; ++nt)
        bf[nt] = *reinterpret_cast<const bf16x8*>(
            &Bc[(nt * 16 + l16) * BSR + ks * 32 + bq * 8]);
      bf16x8 a = mk(A[2 * ks], A[2 * ks + 1]);
#pragma unroll
      for (int nt = 0; nt < 7; ++nt) acc[nt] = MFMA16(a, bf[nt], acc[nt]);
    }
    if (c < 14) stageB_st((c + 1) & 1);  // write other buffer (read done @ c-1)
    __syncthreads();                      // publish stage c+1 / retire chunk c
  }
  // After final barrier: all waves done reading Bs -> safe to alias out_s/xg_s.

  // epilogue: bias + relu -> out_s (wave-private rows), zero-pad cols 100..127
#pragma unroll
  for (int nt = 0; nt < 7; ++nt) {
    const int col = nt * 16 + l16;
#pragma unroll
    for (int r = 0; r < 4; ++r) {
      float v = fmaxf(acc[nt][r] + lb[nt], 0.f);
      out_s[(w * 16 + bq * 4 + r) * OSL + col] = __float2bfloat16((col < 100) ? v : 0.f);
    }
  }
#pragma unroll
  for (int r = 0; r < 4; ++r)
    out_s[(w * 16 + bq * 4 + r) * OSL + 112 + l16] = __float2bfloat16(0.f);

  // ---- Phase B: xg[16 rows][64 gates], wave-private, no barrier ----
  {
    bf16x8 av[4];
#pragma unroll
    for (int s = 0; s < 4; ++s)
      av[s] = *reinterpret_cast<const bf16x8*>(&out_s[(w * 16 + l16) * OSL + s * 32 + bq * 8]);
    f32x4 xacc[4] = {};
#pragma unroll
    for (int gt = 0; gt < 4; ++gt) {
#pragma unroll
      for (int s = 0; s < 4; ++s) {
        bf16x8 b = *reinterpret_cast<const bf16x8*>(&bw2[(gt * 16 + l16) * 128 + s * 32 + bq * 8]);
        xacc[gt] = MFMA16(av[s], b, xacc[gt]);
      }
    }
#pragma unroll
    for (int gt = 0; gt < 4; ++gt) {
      const int gate = gt * 16 + l16;
      const float bias = bih[gate] + bhh[gate];
#pragma unroll
      for (int r = 0; r < 4; ++r)
        xg_s[(w * 16 + bq * 4 + r) * 65 + gate] = xacc[gt][r] + bias;
    }
  }

  // ---- Phase C: beats LSTM, 2 sequences per wave, interleaved ----
  {
    const int cell = lane & 15;
    float wr[16];
#pragma unroll
    for (int u = 0; u < 16; ++u) wr[u] = whh[lane * 16 + u];
    float xv0[8], xv1[8];
#pragma unroll
    for (int t = 0; t < 8; ++t) {
      xv0[t] = xg_s[(w * 16 + t) * 65 + lane];
      xv1[t] = xg_s[(w * 16 + 8 + t) * 65 + lane];
    }
    float h0[16], h1[16];
#pragma unroll
    for (int u = 0; u < 16; ++u) { h0[u] = 0.f; h1[u] = 0.f; }
    float c0 = 0.f, c1 = 0.f;
    const long sg0 = (long)blockIdx.x * 8 + 2 * w;
    const long sg1 = sg0 + 1;
#pragma unroll
    for (int t = 0; t < 8; ++t) {
      float p0 = xv0[t], p1 = xv1[t];
#pragma unroll
      for (int u = 0; u < 16; ++u) { p0 += wr[u] * h0[u]; p1 += wr[u] * h1[u]; }
      const bool istanh = (lane >= 32 && lane < 48);
      float a0 = istanh ? tanhfast(p0) : sigf(p0);
      float a1 = istanh ? tanhfast(p1) : sigf(p1);
      float gi0 = __shfl(a0, cell),      gi1 = __shfl(a1, cell);
      float gf0 = __shfl(a0, cell + 16), gf1 = __shfl(a1, cell + 16);
      float gg0 = __shfl(a0, cell + 32), gg1 = __shfl(a1, cell + 32);
      float go0 = __shfl(a0, cell + 48), go1 = __shfl(a1, cell + 48);
      c0 = gf0 * c0 + gi0 * gg0;
      c1 = gf1 * c1 + gi1 * gg1;
      float hn0 = go0 * tanhfast(c0);
      float hn1 = go1 * tanhfast(c1);
#pragma unroll
      for (int u = 0; u < 16; ++u) { h0[u] = __shfl(hn0, u); h1[u] = __shfl(hn1, u); }
      if (lane < 16) {
        beats[sg0 * 128 + t * 16 + lane] = hn0;
        beats[sg1 * 128 + t * 16 + lane] = hn1;
      }
    }
  }
}

// ---------------------------------------------------------------------------
// Phase 3: bars biLSTM. 1024 seqs, T=4(beats), H=32. Block = 1 seq,
// 256 threads = 2 dirs x 128 gates.
// ---------------------------------------------------------------------------
__global__ __launch_bounds__(256)
void bars_bilstm(const float* __restrict__ fwih, const float* __restrict__ fwhh,
                 const float* __restrict__ fbih, const float* __restrict__ fbhh,
                 const float* __restrict__ rwih, const float* __restrict__ rwhh,
                 const float* __restrict__ rbih, const float* __restrict__ rbhh,
                 const float* __restrict__ beats,
                 float* __restrict__ bars) {
  const int tid = threadIdx.x;
  const int dir = tid >> 7, g = tid & 127;
  const int n = blockIdx.x;
  const float* wih = dir ? rwih : fwih;
  const float* whh = dir ? rwhh : fwhh;
  const float bias = dir ? (rbih[g] + rbhh[g]) : (fbih[g] + fbhh[g]);
  float wi[16], wh[32];
#pragma unroll
  for (int u = 0; u < 16; ++u) wi[u] = wih[g * 16 + u];
#pragma unroll
  for (int u = 0; u < 32; ++u) wh[u] = whh[g * 32 + u];
  __shared__ float xbuf[2][16];
  __shared__ float hbuf[2][32];
  __shared__ float gact[2][128];
  float c = 0.f;
  if (g < 32) hbuf[dir][g] = 0.f;
  __syncthreads();
  for (int t = 0; t < 4; ++t) {
    const int tt = dir ? (3 - t) : t;
    if (g < 16) xbuf[dir][g] = beats[((n * 4 + tt) * 8 + 7) * 16 + g];
    __syncthreads();
    float pre = bias;
#pragma unroll
    for (int u = 0; u < 16; ++u) pre += wi[u] * xbuf[dir][u];
#pragma unroll
    for (int u = 0; u < 32; ++u) pre += wh[u] * hbuf[dir][u];
    gact[dir][g] = (g >= 64 && g < 96) ? tanhfast(pre) : sigf(pre);
    __syncthreads();
    if (g < 32) {
      c = gact[dir][32 + g] * c + gact[dir][g] * gact[dir][64 + g];
      float hn = gact[dir][96 + g] * tanhfast(c);
      hbuf[dir][g] = hn;
      bars[(n * 4 + tt) * 64 + dir * 32 + g] = hn;
    }
    __syncthreads();
  }
}

extern "C" void kernel_launch(void* const* d_in, const int* in_sizes, int n_in,
                              void* d_out, int out_size, void* d_ws, size_t ws_size,
                              hipStream_t stream) {
  const float* ch    = (const float*)d_in[0];
  const float* lin_w = (const float*)d_in[1];
  const float* lin_b = (const float*)d_in[2];
  const float* b_wih = (const float*)d_in[3];
  const float* b_whh = (const float*)d_in[4];
  const float* b_bih = (const float*)d_in[5];
  const float* b_bhh = (const float*)d_in[6];
  const float* f_wih = (const float*)d_in[7];
  const float* f_whh = (const float*)d_in[8];
  const float* f_bih = (const float*)d_in[9];
  const float* f_bhh = (const float*)d_in[10];
  const float* r_wih = (const float*)d_in[11];
  const float* r_whh = (const float*)d_in[12];
  const float* r_bih = (const float*)d_in[13];
  const float* r_bhh = (const float*)d_in[14];

  char* ws = (char*)d_ws;
  __hip_bfloat16* w2  = (__hip_bfloat16*)ws;             // 112*1024*2 = 229376 B
  __hip_bfloat16* bw2 = (__hip_bfloat16*)(ws + 229376);  // 64*128*2   = 16384 B
  float*          out = (float*)d_out;

  prep_kernel<<<480, 256, 0, stream>>>(lin_w, b_wih, w2, bw2);
  fused_encoder<<<512, 256, 0, stream>>>(ch, w2, lin_b, bw2, b_bih, b_bhh,
                                         b_whh, out);
  bars_bilstm<<<1024, 256, 0, stream>>>(f_wih, f_whh, f_bih, f_bhh,
                                        r_wih, r_whh, r_bih, r_bhh,
                                        out, out + 524288);
}

// Round 5
// 227.871 us; speedup vs baseline: 1.1624x; 1.0111x over previous
//
#include <hip/hip_runtime.h>
#include <hip/hip_bf16.h>

typedef float f32x4 __attribute__((ext_vector_type(4)));
typedef short bf16x8 __attribute__((ext_vector_type(8)));

#define MFMA16(a, b, c) __builtin_amdgcn_mfma_f32_16x16x32_bf16(a, b, c, 0, 0, 0)

// Problem constants
constexpr int K1  = 940;    // IN_F
constexpr int KP2 = 1024;   // w2 K stride (zero-padded) = 8 chunks of 128
constexpr int NP  = 112;    // N=100 padded to 7 tiles of 16
constexpr int OSL = 136;    // out_s LDS row stride (bf16)
constexpr int BSR = 136;    // Bs LDS row stride (bf16): 272B, 16B-aligned, reads <=2-way
constexpr int BUFE = NP * BSR;  // elements per Bs buffer (15232; 30464 B)

__device__ __forceinline__ float sigf(float x) { return 1.f / (1.f + __expf(-x)); }
__device__ __forceinline__ float tanhfast(float x) { return 2.f / (1.f + __expf(-2.f * x)) - 1.f; }

__device__ __forceinline__ short f2b(float x) {
  __hip_bfloat16 b = __float2bfloat16(x);
  return *reinterpret_cast<short*>(&b);
}

// ---------------------------------------------------------------------------
// Prep: fold swapaxes(-1,-2) into the weights, convert fp32->bf16, zero-pad.
// w2[n][k] zero for k>=940 or n>=100; bw2 K-padded 100->128.
// ---------------------------------------------------------------------------
__global__ void prep_kernel(const float* __restrict__ lin_w,
                            const float* __restrict__ b_wih,
                            __hip_bfloat16* __restrict__ w2,
                            __hip_bfloat16* __restrict__ bw2) {
  int idx = blockIdx.x * 256 + threadIdx.x;
  if (idx < NP * KP2) {
    int n = idx >> 10, k = idx & 1023;
    float v = 0.f;
    if (n < 100 && k < K1) {
      int c10 = k / 94, rem = k - c10 * 94;
      int c2 = rem / 47, c47 = rem - c2 * 47;
      int f = c10 * 94 + c47 * 2 + c2;
      v = lin_w[n * K1 + f];
    }
    w2[idx] = __float2bfloat16(v);
  } else {
    int i2 = idx - NP * KP2;
    if (i2 < 64 * 128) {
      int g = i2 >> 7, k = i2 & 127;
      bw2[i2] = __float2bfloat16((k < 100) ? b_wih[g * 100 + k] : 0.f);
    }
  }
}

// ---------------------------------------------------------------------------
// Mega-fused: staged GEMM (128-k chunks, 8 barriers) -> xg GEMM -> beats LSTM
// -> bars biLSTM (block's 64 rows = 8 seqs = exactly 2 bar-sequences).
// Block = 256 threads = 4 waves; wave w owns rows w*16..w*16+15 end-to-end.
//   B (w2): double-buffered LDS chunks (112 x 128k = 28 KB), reg-staged;
//           loads for chunk c+1 issued before compute of chunk c.
//   A: HBM, double-buffered one chunk ahead.
//   Phases B/C: wave-private rows, barrier-free. Bars: via hlast LDS.
// LDS: Bs dbuf 60928 B, unioned with out_s(17408)+xg_s(16640)+bars bufs.
// launch_bounds (256,2): cap 256 VGPR >= ~180 needed (R1: never cap < need).
// ---------------------------------------------------------------------------
__global__ __launch_bounds__(256, 2)
void fused_encoder(const float* __restrict__ ch,
                   const __hip_bfloat16* __restrict__ w2,
                   const float* __restrict__ lin_b,
                   const __hip_bfloat16* __restrict__ bw2,
                   const float* __restrict__ bih,
                   const float* __restrict__ bhh,
                   const float* __restrict__ whh,
                   const float* __restrict__ fwih, const float* __restrict__ fwhh,
                   const float* __restrict__ fbih, const float* __restrict__ fbhh,
                   const float* __restrict__ rwih, const float* __restrict__ rwhh,
                   const float* __restrict__ rbih, const float* __restrict__ rbhh,
                   float* __restrict__ beats,
                   float* __restrict__ bars) {
  __shared__ __align__(16) char smem[2 * BUFE * 2];                 // 60928 B
  __hip_bfloat16* Bs    = reinterpret_cast<__hip_bfloat16*>(smem);
  __hip_bfloat16* out_s = reinterpret_cast<__hip_bfloat16*>(smem);  // [0,17408)
  float*          xg_s  = reinterpret_cast<float*>(smem + 17408);   // 16640 B
  float (*hlast)[16]    = reinterpret_cast<float(*)[16]>(smem + 34048);  // 512 B
  float (*hb)[32]       = reinterpret_cast<float(*)[32]>(smem + 34560);  // 256 B
  float (*gact)[128]    = reinterpret_cast<float(*)[128]>(smem + 34816); // 1024 B

  const int tid = threadIdx.x;
  const int w = tid >> 6, lane = tid & 63;
  const int l16 = lane & 15, bq = lane >> 4;

  const int mbase = blockIdx.x * 64 + w * 16;        // wave's first row
  const float* ar = ch + (long)(mbase + l16) * K1 + bq * 8;

  float lb[7];
#pragma unroll
  for (int nt = 0; nt < 7; ++nt) {
    int col = nt * 16 + l16;
    lb[nt] = (col < 100) ? lin_b[col] : 0.f;
  }

  auto mk = [&](float4 lo, float4 hi) -> bf16x8 {
    return bf16x8{f2b(lo.x), f2b(lo.y), f2b(lo.z), f2b(lo.w),
                  f2b(hi.x), f2b(hi.y), f2b(hi.z), f2b(hi.w)};
  };

  // ---- Phase A: 8 chunks of 128 k ----
  f32x4 acc[7] = {};
  float4 Ab[2][8];   // A chunk = 128 k = 32 fp32/lane, double-buffered
  bf16x8 bst[8];     // B staging registers (global -> LDS), 128 B/thread

  const float4 f40{0.f, 0.f, 0.f, 0.f};
  // A chunk c covers k = c*128 .. c*128+127; lane frag ks uses k=c*128+ks*32+bq*8
  auto ldA = [&](int c, float4* d) {
    const float* p = ar + c * 128;
    if (c < 7) {
#pragma unroll
      for (int ks = 0; ks < 4; ++ks) {
        d[2 * ks]     = *reinterpret_cast<const float4*>(p + ks * 32);
        d[2 * ks + 1] = *reinterpret_cast<const float4*>(p + ks * 32 + 4);
      }
    } else {  // c==7: k 896..939 valid, rest masked (w2 zero-padded there too)
      d[0] = *reinterpret_cast<const float4*>(p);          // 896+bq*8 .. +7
      d[1] = *reinterpret_cast<const float4*>(p + 4);
      d[2] = (bq <= 1) ? *reinterpret_cast<const float4*>(p + 32) : f40;  // 928..939
      d[3] = (bq == 0) ? *reinterpret_cast<const float4*>(p + 36) : f40;  // 932..935
      d[4] = d[5] = d[6] = d[7] = f40;                     // k >= 960
    }
  };

  // B staging: threads t<224: row sn=t>>1, k-half kh=(t&1)*64 (128 B each)
  const int sn = tid >> 1, kh = (tid & 1) * 64;
  auto stageB_ld = [&](int c) {
    if (sn < NP) {
      const __hip_bfloat16* src = w2 + sn * KP2 + c * 128 + kh;
#pragma unroll
      for (int j = 0; j < 8; ++j)
        bst[j] = *reinterpret_cast<const bf16x8*>(src + j * 8);
    }
  };
  auto stageB_st = [&](int buf) {
    if (sn < NP) {
      __hip_bfloat16* dst = Bs + buf * BUFE + sn * BSR + kh;
#pragma unroll
      for (int j = 0; j < 8; ++j)
        *reinterpret_cast<bf16x8*>(dst + j * 8) = bst[j];
    }
  };

  stageB_ld(0);
  stageB_st(0);
  ldA(0, Ab[0]);
  __syncthreads();

  for (int c = 0; c < 8; ++c) {
    if (c < 7) {
      stageB_ld(c + 1);              // global B loads land during compute
      ldA(c + 1, Ab[(c + 1) & 1]);   // HBM A prefetch, one chunk ahead
    }
    const __hip_bfloat16* Bc = Bs + (c & 1) * BUFE;
    float4* A = Ab[c & 1];
#pragma unroll
    for (int ks = 0; ks < 4; ++ks) {
      bf16x8 bf[7];
#pragma unroll
      for (int nt = 0; nt < 7; ++nt)
        bf[nt] = *reinterpret_cast<const bf16x8*>(
            &Bc[(nt * 16 + l16) * BSR + ks * 32 + bq * 8]);
      bf16x8 a = mk(A[2 * ks], A[2 * ks + 1]);
#pragma unroll
      for (int nt = 0; nt < 7; ++nt) acc[nt] = MFMA16(a, bf[nt], acc[nt]);
    }
    if (c < 7) stageB_st((c + 1) & 1);  // other buffer; its readers done @ c-1
    __syncthreads();
  }
  // All waves past final barrier: Bs dead -> alias out_s/xg_s/bars bufs.

  // epilogue: bias + relu -> out_s (wave-private rows), zero-pad cols 100..127
#pragma unroll
  for (int nt = 0; nt < 7; ++nt) {
    const int col = nt * 16 + l16;
#pragma unroll
    for (int r = 0; r < 4; ++r) {
      float v = fmaxf(acc[nt][r] + lb[nt], 0.f);
      out_s[(w * 16 + bq * 4 + r) * OSL + col] = __float2bfloat16((col < 100) ? v : 0.f);
    }
  }
#pragma unroll
  for (int r = 0; r < 4; ++r)
    out_s[(w * 16 + bq * 4 + r) * OSL + 112 + l16] = __float2bfloat16(0.f);

  // ---- Phase B: xg[16 rows][64 gates], wave-private, no barrier ----
  {
    bf16x8 av[4];
#pragma unroll
    for (int s = 0; s < 4; ++s)
      av[s] = *reinterpret_cast<const bf16x8*>(&out_s[(w * 16 + l16) * OSL + s * 32 + bq * 8]);
    f32x4 xacc[4] = {};
#pragma unroll
    for (int gt = 0; gt < 4; ++gt) {
#pragma unroll
      for (int s = 0; s < 4; ++s) {
        bf16x8 b = *reinterpret_cast<const bf16x8*>(&bw2[(gt * 16 + l16) * 128 + s * 32 + bq * 8]);
        xacc[gt] = MFMA16(av[s], b, xacc[gt]);
      }
    }
#pragma unroll
    for (int gt = 0; gt < 4; ++gt) {
      const int gate = gt * 16 + l16;
      const float bias = bih[gate] + bhh[gate];
#pragma unroll
      for (int r = 0; r < 4; ++r)
        xg_s[(w * 16 + bq * 4 + r) * 65 + gate] = xacc[gt][r] + bias;
    }
  }

  // ---- Phase C: beats LSTM, 2 sequences per wave, interleaved ----
  {
    const int cell = lane & 15;
    float wr[16];
#pragma unroll
    for (int u = 0; u < 16; ++u) wr[u] = whh[lane * 16 + u];
    float xv0[8], xv1[8];
#pragma unroll
    for (int t = 0; t < 8; ++t) {
      xv0[t] = xg_s[(w * 16 + t) * 65 + lane];
      xv1[t] = xg_s[(w * 16 + 8 + t) * 65 + lane];
    }
    float h0[16], h1[16];
#pragma unroll
    for (int u = 0; u < 16; ++u) { h0[u] = 0.f; h1[u] = 0.f; }
    float c0 = 0.f, c1 = 0.f;
    const long sg0 = (long)blockIdx.x * 8 + 2 * w;
    const long sg1 = sg0 + 1;
#pragma unroll
    for (int t = 0; t < 8; ++t) {
      float p0 = xv0[t], p1 = xv1[t];
#pragma unroll
      for (int u = 0; u < 16; ++u) { p0 += wr[u] * h0[u]; p1 += wr[u] * h1[u]; }
      const bool istanh = (lane >= 32 && lane < 48);
      float a0 = istanh ? tanhfast(p0) : sigf(p0);
      float a1 = istanh ? tanhfast(p1) : sigf(p1);
      float gi0 = __shfl(a0, cell),      gi1 = __shfl(a1, cell);
      float gf0 = __shfl(a0, cell + 16), gf1 = __shfl(a1, cell + 16);
      float gg0 = __shfl(a0, cell + 32), gg1 = __shfl(a1, cell + 32);
      float go0 = __shfl(a0, cell + 48), go1 = __shfl(a1, cell + 48);
      c0 = gf0 * c0 + gi0 * gg0;
      c1 = gf1 * c1 + gi1 * gg1;
      float hn0 = go0 * tanhfast(c0);
      float hn1 = go1 * tanhfast(c1);
#pragma unroll
      for (int u = 0; u < 16; ++u) { h0[u] = __shfl(hn0, u); h1[u] = __shfl(hn1, u); }
      if (lane < 16) {
        beats[sg0 * 128 + t * 16 + lane] = hn0;
        beats[sg1 * 128 + t * 16 + lane] = hn1;
        if (t == 7) {                       // last-frac h -> bars input
          hlast[2 * w][lane]     = hn0;
          hlast[2 * w + 1][lane] = hn1;
        }
      }
    }
  }
  __syncthreads();  // publish hlast to all waves

  // ---- Phase D: bars biLSTM for this block's 2 bar-sequences. ----
  // 256 threads = 2 dirs x 128 gates (dir is wave-uniform: waves 0,1 fwd).
  {
    const int dir = tid >> 7, g = tid & 127;
    const float* wihp = dir ? rwih : fwih;
    const float* whhp = dir ? rwhh : fwhh;
    const float bias = dir ? (rbih[g] + rbhh[g]) : (fbih[g] + fbhh[g]);
    float wi[16], wh[32];
#pragma unroll
    for (int u = 0; u < 16; ++u) wi[u] = wihp[g * 16 + u];
#pragma unroll
    for (int u = 0; u < 32; ++u) wh[u] = whhp[g * 32 + u];
    for (int b2 = 0; b2 < 2; ++b2) {
      const int n = blockIdx.x * 2 + b2;
      float c = 0.f;
      if (g < 32) hb[dir][g] = 0.f;
      __syncthreads();
      for (int t = 0; t < 4; ++t) {
        const int tt = dir ? (3 - t) : t;
        float pre = bias;
#pragma unroll
        for (int u = 0; u < 16; ++u) pre += wi[u] * hlast[b2 * 4 + tt][u];
#pragma unroll
        for (int u = 0; u < 32; ++u) pre += wh[u] * hb[dir][u];
        gact[dir][g] = (g >= 64 && g < 96) ? tanhfast(pre) : sigf(pre);
        __syncthreads();
        if (g < 32) {
          c = gact[dir][32 + g] * c + gact[dir][g] * gact[dir][64 + g];
          float hn = gact[dir][96 + g] * tanhfast(c);
          hb[dir][g] = hn;
          bars[(n * 4 + tt) * 64 + dir * 32 + g] = hn;
        }
        __syncthreads();
      }
    }
  }
}

extern "C" void kernel_launch(void* const* d_in, const int* in_sizes, int n_in,
                              void* d_out, int out_size, void* d_ws, size_t ws_size,
                              hipStream_t stream) {
  const float* ch    = (const float*)d_in[0];
  const float* lin_w = (const float*)d_in[1];
  const float* lin_b = (const float*)d_in[2];
  const float* b_wih = (const float*)d_in[3];
  const float* b_whh = (const float*)d_in[4];
  const float* b_bih = (const float*)d_in[5];
  const float* b_bhh = (const float*)d_in[6];
  const float* f_wih = (const float*)d_in[7];
  const float* f_whh = (const float*)d_in[8];
  const float* f_bih = (const float*)d_in[9];
  const float* f_bhh = (const float*)d_in[10];
  const float* r_wih = (const float*)d_in[11];
  const float* r_whh = (const float*)d_in[12];
  const float* r_bih = (const float*)d_in[13];
  const float* r_bhh = (const float*)d_in[14];

  char* ws = (char*)d_ws;
  __hip_bfloat16* w2  = (__hip_bfloat16*)ws;             // 112*1024*2 = 229376 B
  __hip_bfloat16* bw2 = (__hip_bfloat16*)(ws + 229376);  // 64*128*2   = 16384 B
  float*          out = (float*)d_out;

  prep_kernel<<<480, 256, 0, stream>>>(lin_w, b_wih, w2, bw2);
  fused_encoder<<<512, 256, 0, stream>>>(ch, w2, lin_b, bw2, b_bih, b_bhh,
                                         b_whh,
                                         f_wih, f_whh, f_bih, f_bhh,
                                         r_wih, r_whh, r_bih, r_bhh,
                                         out, out + 524288);
}